// Round 7
// baseline (73.773 us; speedup 1.0000x reference)
//
#include <hip/hip_runtime.h>
#include <hip/hip_bf16.h>
#include <stdint.h>

#define IN_F 4096
#define OUT_F 4096
#define NBKT 256
#define SBLOCKS 410          // 410 * 8192 = 3,358,720 >= NNZ
#define REC_PER_SB 8192
#define QCAP 3968u           // per-quarter list: mean 3277, sigma 57, +12 sigma
#define THRESH 0.01f

typedef unsigned int u32;
typedef unsigned short u16;
typedef __attribute__((ext_vector_type(8))) short short8;   // 8 bf16 = 4 VGPR
typedef __attribute__((ext_vector_type(4))) float f32x4;

// ws layout:
//   [0)        u16 xB[512][64][8]            (512 KB)  B-frag layout: ((k>>3)*64+b)*8+(k&7)
//   [524288)   u32 offA[410][257]            (412 KB)  per-scatter-block bucket prefix
//   [950272)   u32 sortg[410][8192]          (13.4 MB) block-major bucket-sorted records
static const size_t WS_XB = 0;
static const size_t WS_OFFA = 524288;
static const size_t WS_SORT = 950272;
static const size_t WS_NEEDED = WS_SORT + (size_t)SBLOCKS * REC_PER_SB * 4;

static __device__ __forceinline__ u16 f2bf(float v) {
  __hip_bfloat16 h = __float2bfloat16(v);
  return *reinterpret_cast<u16*>(&h);
}

// gate + bf16 + MFMA-B-fragment layout: xB[((k>>3)*64 + b)*8 + (k&7)] = bf16(gate(x[b][k]))
__global__ __launch_bounds__(256) void k_xb(const float* __restrict__ x, u16* __restrict__ xB) {
  const int tid = blockIdx.x * 256 + threadIdx.x;   // 32768 threads
  const int b = tid & 63;
  const int kg = tid >> 6;                          // 0..511
  const float* src = x + (size_t)b * IN_F + kg * 8;
  const f32x4 a0 = *reinterpret_cast<const f32x4*>(src);
  const f32x4 a1 = *reinterpret_cast<const f32x4*>(src + 4);
  short8 o;
#pragma unroll
  for (int e = 0; e < 4; ++e) {
    float v = a0[e]; v = (v > THRESH) ? v : 0.0f; o[e] = (short)f2bf(v);
  }
#pragma unroll
  for (int e = 0; e < 4; ++e) {
    float v = a1[e]; v = (v > THRESH) ? v : 0.0f; o[4 + e] = (short)f2bf(v);
  }
  *reinterpret_cast<short8*>(xB + ((size_t)kg * 64 + b) * 8) = o;   // coalesced 16B
}

// block-major counting sort: each block sorts its 8192 records by bucket in LDS,
// dumps one coalesced 32KB segment + its 257-entry prefix.
__global__ __launch_bounds__(1024) void k_scatter(const int* __restrict__ rows,
                                                  const int* __restrict__ cols,
                                                  const float* __restrict__ vals, u32 nnz,
                                                  u32* __restrict__ offA,
                                                  u32* __restrict__ sortg) {
  __shared__ u32 cnt[NBKT];
  __shared__ u32 pref[NBKT + 1];
  __shared__ u32 srt[REC_PER_SB];   // 32 KB
  const int tid = threadIdx.x;
  const int lane = tid & 63;
  const int wid = tid >> 6;
  if (tid < NBKT) cnt[tid] = 0;
  __syncthreads();
  const u32 base = blockIdx.x * (u32)REC_PER_SB;
  u32 rec[8], bkt[8], rk[8];
#pragma unroll
  for (int j = 0; j < 8; ++j) {
    const u32 i = base + (u32)j * 1024u + tid;
    bkt[j] = 0xffffffffu;
    if (i < nnz) {
      const u32 r = (u32)rows[i] & 4095u;
      const u32 c = (u32)cols[i] & 4095u;
      rec[j] = (c << 20) | ((r & 15u) << 16) | (u32)f2bf(vals[i]);
      bkt[j] = r >> 4;
      rk[j] = atomicAdd(&cnt[bkt[j]], 1u);
    }
  }
  __syncthreads();
  // wave-0 exclusive prefix over 256 bins (4 bins/lane + wave scan)
  if (wid == 0) {
    u32 a[4]; u32 s = 0;
#pragma unroll
    for (int j = 0; j < 4; ++j) { a[j] = cnt[lane * 4 + j]; s += a[j]; }
    u32 x = s;
#pragma unroll
    for (int d = 1; d < 64; d <<= 1) {
      const u32 y = (u32)__shfl_up((int)x, d, 64);
      if (lane >= d) x += y;
    }
    u32 e = x - s;
#pragma unroll
    for (int j = 0; j < 4; ++j) { pref[lane * 4 + j] = e; e += a[j]; }
    if (lane == 63) pref[256] = e;   // block total
  }
  __syncthreads();
#pragma unroll
  for (int j = 0; j < 8; ++j)
    if (bkt[j] != 0xffffffffu) srt[pref[bkt[j]] + rk[j]] = rec[j];
  if (tid < NBKT + 1) offA[(size_t)blockIdx.x * (NBKT + 1) + tid] = pref[tid];
  __syncthreads();
  // coalesced segment dump (16B per thread per j)
  u32* dst = sortg + (size_t)blockIdx.x * REC_PER_SB;
#pragma unroll
  for (int j = 0; j < 2; ++j) {
    const int o = j * 4096 + tid * 4;
    const uint4 v = *reinterpret_cast<uint4*>(&srt[o]);
    *reinterpret_cast<uint4*>(&dst[o]) = v;   // garbage beyond total: never read
  }
}

// one block per bucket: 4-deep pipelined run gather -> ballot-partitioned quarter
// lists in LDS -> dense LDS-atomic densify -> MFMA
__global__ __launch_bounds__(1024, 1) void k_accum(const u32* __restrict__ sortg,
                                                   const u32* __restrict__ offA,
                                                   const u16* __restrict__ xB,
                                                   const float* __restrict__ bias,
                                                   float* __restrict__ out) {
  __shared__ float W[16 * 1024];    // 64 KB; reused as reduction scratch at the end
  __shared__ u32 Q[4][QCAP];        // 62 KB quarter-partitioned records
  __shared__ u32 Gs[SBLOCKS], Gl[SBLOCKS];
  __shared__ u32 qcur[4];
  const int tid = threadIdx.x;
  const int lane = tid & 63;
  const int w = tid >> 6;           // wave 0..15
  const u32 t = blockIdx.x;

  // per-run (start,len) for this bucket
  if (tid < SBLOCKS) {
    const u32 a = offA[(size_t)tid * (NBKT + 1) + t];
    const u32 b = offA[(size_t)tid * (NBKT + 1) + t + 1];
    Gs[tid] = (u32)tid * REC_PER_SB + a;
    Gl[tid] = b - a;
  }
  if (tid < 4) qcur[tid] = 0;
  __syncthreads();

  // phase 1: gather runs 4-at-a-time (independent loads -> MLP), ballot-partition
  // into 4 quarter lists (append-contiguous ds_writes, one LDS atomic per ballot)
  for (int ch = 0; ch < 7; ++ch) {
    u32 rc4[4], ln4[4]; int g4[4];
#pragma unroll
    for (int j = 0; j < 4; ++j) {
      const int idx = ch * 4 + j;
      g4[j] = w + 16 * idx;
      ln4[j] = 0; rc4[j] = 0;
      if (g4[j] < SBLOCKS) {
        ln4[j] = Gl[g4[j]];
        if ((u32)lane < ln4[j]) rc4[j] = sortg[Gs[g4[j]] + lane];
      }
    }
#pragma unroll
    for (int j = 0; j < 4; ++j) {
      const u32 L = ln4[j];
      const bool vld = (u32)lane < L;
      const u32 r = rc4[j];
      const u32 qv = r >> 30;
#pragma unroll
      for (u32 qq = 0; qq < 4; ++qq) {
        const bool m = vld && (qv == qq);
        const unsigned long long mask = __ballot(m);
        if (mask) {
          const int leader = __builtin_ctzll(mask);
          u32 bas = 0;
          if (lane == leader) bas = atomicAdd(&qcur[qq], (u32)__popcll(mask));
          bas = (u32)__shfl((int)bas, leader, 64);
          if (m) {
            const u32 pos = bas + (u32)__popcll(mask & ((1ull << lane) - 1ull));
            if (pos < QCAP) Q[qq][pos] = r;
          }
        }
      }
      // rare long-run tail (P ~ 3e-7 per run)
      for (u32 k = 64u + (u32)lane; k < L; k += 64u) {
        const u32 r2 = sortg[Gs[g4[j]] + k];
        const u32 pos = atomicAdd(&qcur[r2 >> 30], 1u);
        if (pos < QCAP) Q[r2 >> 30][pos] = r2;
      }
    }
  }

  f32x4 acc0 = {0.f, 0.f, 0.f, 0.f}, acc1 = {0.f, 0.f, 0.f, 0.f};
  f32x4 acc2 = {0.f, 0.f, 0.f, 0.f}, acc3 = {0.f, 0.f, 0.f, 0.f};
  const int row = lane & 15;       // A-frag row / C col index
  const int e8 = (lane >> 4) * 8;  // A/B-frag k sub-offset

  for (int q = 0; q < 4; ++q) {
    __syncthreads();               // phase-1 writes / previous quarter's A-reads done
    const f32x4 z = {0.f, 0.f, 0.f, 0.f};
#pragma unroll
    for (int j = 0; j < 4; ++j)
      *reinterpret_cast<f32x4*>(&W[j * 4096 + tid * 4]) = z;
    __syncthreads();
    // dense all-lane scatter-add of this quarter's list (f32: exact duplicates)
    u32 m = qcur[q]; if (m > QCAP) m = QCAP;
    for (u32 i = (u32)tid; i < m; i += 1024u) {
      const u32 rc = Q[q][i];
      const u32 rl = (rc >> 16) & 15u;
      const u32 cl = ((rc >> 20) & 1023u) ^ ((rl & 7u) << 3);   // 8-elem XOR swizzle
      __hip_atomic_fetch_add(&W[rl * 1024u + cl], __uint_as_float(rc << 16),
                             __ATOMIC_RELAXED, __HIP_MEMORY_SCOPE_WORKGROUP);
    }
    __syncthreads();
    // dense MFMA over this quarter; wave w covers local k [w*64, w*64+64)
#pragma unroll
    for (int s = 0; s < 2; ++s) {
      const int klb = w * 64 + s * 32 + e8;                 // 8-aligned local k
      const int sw = klb ^ ((row & 7) << 3);                // matches write swizzle
      const f32x4 wa = *reinterpret_cast<const f32x4*>(&W[row * 1024 + sw]);
      const f32x4 wb = *reinterpret_cast<const f32x4*>(&W[row * 1024 + (sw + 4)]);
      short8 af;
#pragma unroll
      for (int e = 0; e < 4; ++e) af[e] = (short)f2bf(wa[e]);
#pragma unroll
      for (int e = 0; e < 4; ++e) af[4 + e] = (short)f2bf(wb[e]);
      const int kabs = q * 1024 + klb;
      const u16* bp = xB + (size_t)(kabs >> 3) * 512 + (u32)(lane & 15) * 8;
      const short8 b0 = *reinterpret_cast<const short8*>(bp);
      const short8 b1 = *reinterpret_cast<const short8*>(bp + 128);
      const short8 b2 = *reinterpret_cast<const short8*>(bp + 256);
      const short8 b3 = *reinterpret_cast<const short8*>(bp + 384);
      acc0 = __builtin_amdgcn_mfma_f32_16x16x32_bf16(af, b0, acc0, 0, 0, 0);
      acc1 = __builtin_amdgcn_mfma_f32_16x16x32_bf16(af, b1, acc1, 0, 0, 0);
      acc2 = __builtin_amdgcn_mfma_f32_16x16x32_bf16(af, b2, acc2, 0, 0, 0);
      acc3 = __builtin_amdgcn_mfma_f32_16x16x32_bf16(af, b3, acc3, 0, 0, 0);
    }
  }
  __syncthreads();
  // write per-wave C partials to scratch: scr[((w*4+nt)*16 + crow)*16 + ccol]
  {
    const int ccol = lane & 15;                 // C col = lane&15 (m89-verified)
    const int rb = (lane >> 4) * 4;             // C row = (lane>>4)*4 + reg
#pragma unroll
    for (int qq = 0; qq < 4; ++qq) W[((w * 4 + 0) * 16 + rb + qq) * 16 + ccol] = acc0[qq];
#pragma unroll
    for (int qq = 0; qq < 4; ++qq) W[((w * 4 + 1) * 16 + rb + qq) * 16 + ccol] = acc1[qq];
#pragma unroll
    for (int qq = 0; qq < 4; ++qq) W[((w * 4 + 2) * 16 + rb + qq) * 16 + ccol] = acc2[qq];
#pragma unroll
    for (int qq = 0; qq < 4; ++qq) W[((w * 4 + 3) * 16 + rb + qq) * 16 + ccol] = acc3[qq];
  }
  __syncthreads();
  // reduce 16 wave-partials -> out(row rl, batch b); coalesced 64B store runs
  const int rl = tid & 15;
  const int b = tid >> 4;
  float sum = bias[t * 16u + rl];
#pragma unroll
  for (int w2 = 0; w2 < 16; ++w2)
    sum += W[((w2 * 4 + (b >> 4)) * 16 + rl) * 16 + (b & 15)];
  out[(size_t)b * OUT_F + t * 16u + rl] = sum;
}

// ---- fallback path (only if ws too small): correct but slow ----
__global__ __launch_bounds__(256) void k_bias_init(const float* __restrict__ bias,
                                                   float* __restrict__ out) {
  const int i = blockIdx.x * 256 + threadIdx.x;
  if (i < 64 * OUT_F) out[i] = bias[i & (OUT_F - 1)];
}

__global__ __launch_bounds__(256) void k_fallback(const int* __restrict__ rows,
                                                  const int* __restrict__ cols,
                                                  const float* __restrict__ vals,
                                                  const float* __restrict__ x,
                                                  float* __restrict__ out, int nnz) {
  const int gw = (int)(((u32)blockIdx.x * blockDim.x + threadIdx.x) >> 6);
  const int lane = threadIdx.x & 63;
  const int nw = (int)(((u32)gridDim.x * blockDim.x) >> 6);
  for (int i = gw; i < nnz; i += nw) {
    const int r = rows[i];
    const int c = cols[i];
    const float v = vals[i];
    const float xv = x[lane * IN_F + c];
    if (xv > THRESH) atomicAdd(&out[(size_t)lane * OUT_F + r], v * xv);
  }
}

extern "C" void kernel_launch(void* const* d_in, const int* in_sizes, int n_in,
                              void* d_out, int out_size, void* d_ws, size_t ws_size,
                              hipStream_t stream) {
  const float* x = (const float*)d_in[0];
  const int* rows = (const int*)d_in[1];
  const int* cols = (const int*)d_in[2];
  const float* vals = (const float*)d_in[3];
  const float* bias = (const float*)d_in[4];
  float* out = (float*)d_out;
  const int nnz = in_sizes[1];

  if (ws_size >= WS_NEEDED && nnz <= SBLOCKS * REC_PER_SB) {
    u16* xB = (u16*)((char*)d_ws + WS_XB);
    u32* offA = (u32*)((char*)d_ws + WS_OFFA);
    u32* sortg = (u32*)((char*)d_ws + WS_SORT);
    k_xb<<<128, 256, 0, stream>>>(x, xB);
    k_scatter<<<SBLOCKS, 1024, 0, stream>>>(rows, cols, vals, (u32)nnz, offA, sortg);
    k_accum<<<NBKT, 1024, 0, stream>>>(sortg, offA, xB, bias, out);
  } else {
    k_bias_init<<<(64 * OUT_F + 255) / 256, 256, 0, stream>>>(bias, out);
    k_fallback<<<4096, 256, 0, stream>>>(rows, cols, vals, x, out, nnz);
  }
}